// Round 11
// baseline (208.101 us; speedup 1.0000x reference)
//
#include <hip/hip_runtime.h>
#include <hip/hip_bf16.h>

#define BB 2
#define NN 2048
#define DD 768
#define EE 8
#define FF 3072
#define TOK (BB*NN)       // 4096
#define ROWS_CAP 9216
#define TILES 72

typedef __attribute__((ext_vector_type(8))) __bf16 bf16x8;
typedef __attribute__((ext_vector_type(4))) float floatx4;

// ---------- ws layout (bytes) ----------
#define OFF_CTRL    0ull
#define OFF_V       1024ull
#define OFF_TOKE    17408ull
#define OFF_TOKW    50176ull
#define OFF_ROWTOK  82944ull
#define OFF_ROWW    119808ull
#define OFF_SLOT    156672ull
#define OFF_FEATS   189440ull
#define OFF_W2T     222208ull               // ushort[8*768*3072] (w2^T: [e][d][f'], f' perm)
#define OFF_XBF     37970944ull             // ushort[4096*768]
#define OFF_W1T     44262400ull             // ushort[8*3072*768] (w1^T: [e][f][d])
#define OFF_H       82011136ull             // ushort[9216*3072]  (f' perm layout)
#define OFF_Y       OFF_XBF                 // float[9216*768], aliases dead XBF+W1T

__device__ __forceinline__ ushort f2b(float f) {
    union { float f; unsigned int i; } v; v.f = f;
    unsigned int u = v.i;
    unsigned int r = (u + 0x7FFFu + ((u >> 16) & 1u)) >> 16;
    return (ushort)r;
}
__device__ __forceinline__ unsigned int pk2(float lo, float hi) {
    union { float f; unsigned int u; } a, b;
    a.f = lo; b.f = hi;
    unsigned int ra = ((a.u + 0x7FFFu + ((a.u >> 16) & 1u)) >> 16) & 0xFFFFu;
    unsigned int rb = (b.u + 0x7FFFu + ((b.u >> 16) & 1u)) & 0xFFFF0000u;
    return ra | rb;
}
__device__ __forceinline__ float gelu_f(float x) {
    float z = 0.7978845608028654f * x * (1.f + 0.044715f * x * x);
    z = fminf(fmaxf(z, -12.f), 12.f);
    float e = __expf(2.f * z);
    return 0.5f * x * (1.f + (e - 1.f) / (e + 1.f));
}
__device__ __forceinline__ void gload16(const ushort* g, ushort* l) {
    __builtin_amdgcn_global_load_lds((const __attribute__((address_space(1))) void*)g,
                                     (__attribute__((address_space(3))) void*)l,
                                     16, 0, 0);
}

// ---------- complex / Mobius helpers ----------
struct cplx { float x, y; };
__device__ __forceinline__ cplx cmulc(cplx a, cplx b) { return {a.x*b.x - a.y*b.y, a.x*b.y + a.y*b.x}; }
__device__ __forceinline__ cplx caddc(cplx a, cplx b) { return {a.x + b.x, a.y + b.y}; }
__device__ __forceinline__ cplx cdivc(cplx a, cplx b) {
    float s = 1.f / (b.x*b.x + b.y*b.y);
    return {(a.x*b.x + a.y*b.y)*s, (a.y*b.x - a.x*b.y)*s};
}
struct mob { cplx m00, m01, m10, m11; };
__device__ __forceinline__ mob mmul(const mob& A, const mob& B) {
    mob C;
    C.m00 = caddc(cmulc(A.m00, B.m00), cmulc(A.m01, B.m10));
    C.m01 = caddc(cmulc(A.m00, B.m01), cmulc(A.m01, B.m11));
    C.m10 = caddc(cmulc(A.m10, B.m00), cmulc(A.m11, B.m10));
    C.m11 = caddc(cmulc(A.m10, B.m01), cmulc(A.m11, B.m11));
    return C;
}
__device__ __forceinline__ void mnorm(mob& A) {
    float s = fabsf(A.m00.x);
    s = fmaxf(s, fabsf(A.m00.y)); s = fmaxf(s, fabsf(A.m01.x)); s = fmaxf(s, fabsf(A.m01.y));
    s = fmaxf(s, fabsf(A.m10.x)); s = fmaxf(s, fabsf(A.m10.y)); s = fmaxf(s, fabsf(A.m11.x));
    s = fmaxf(s, fabsf(A.m11.y));
    float r = 1.f / fmaxf(s, 1e-30f);
    A.m00.x *= r; A.m00.y *= r; A.m01.x *= r; A.m01.y *= r;
    A.m10.x *= r; A.m10.y *= r; A.m11.x *= r; A.m11.y *= r;
}
__device__ __forceinline__ mob mstep(cplx a, const mob& P) {
    mob C;
    C.m00 = {a.x*P.m00.x - a.y*P.m00.y - P.m10.x, a.x*P.m00.y + a.y*P.m00.x - P.m10.y};
    C.m01 = {a.x*P.m01.x - a.y*P.m01.y - P.m11.x, a.x*P.m01.y + a.y*P.m01.x - P.m11.y};
    C.m10 = P.m00; C.m11 = P.m01;
    return C;
}
__device__ __forceinline__ void mstore(float* s, const mob& A) {
    s[0]=A.m00.x; s[1]=A.m00.y; s[2]=A.m01.x; s[3]=A.m01.y;
    s[4]=A.m10.x; s[5]=A.m10.y; s[6]=A.m11.x; s[7]=A.m11.y;
}
__device__ __forceinline__ mob mload(const float* s) {
    mob A;
    A.m00 = {s[0], s[1]}; A.m01 = {s[2], s[3]};
    A.m10 = {s[4], s[5]}; A.m11 = {s[6], s[7]};
    return A;
}

// ============ 64x64 transpose-convert (unchanged, round 8 swizzle) ============
template<bool PERM>
__device__ __forceinline__ void tcvt64_body(
    const float* __restrict__ src, ushort* __restrict__ dst,
    int Rs, int Cs, int r0, int c0, ushort* __restrict__ tT /* [64*72] */, int tid)
{
    int lr = tid >> 2;
    int lc0 = (tid & 3) * 16;
    const float* sp = src + (size_t)(r0 + lr) * Cs + c0 + lc0;
    float4 v[4];
    #pragma unroll
    for (int u = 0; u < 4; u++) v[u] = *(const float4*)(sp + 4*u);
    int chw = lr >> 3, wbit = lr & 7;
    #pragma unroll
    for (int u = 0; u < 4; u++) {
        float vs[4] = {v[u].x, v[u].y, v[u].z, v[u].w};
        #pragma unroll
        for (int e2 = 0; e2 < 4; e2++) {
            int col = lc0 + 4*u + e2;
            int g = (col >> 4) & 3;
            tT[col * 72 + ((chw ^ g) << 3) + wbit] = f2b(vs[e2]);
        }
    }
    __syncthreads();
    int p = tid & 7;
    #pragma unroll
    for (int pass = 0; pass < 2; pass++) {
        int c = (tid >> 3) + pass * 32;
        int g = (c >> 4) & 3;
        int chl = p ^ g;
        int a64 = chl * 8;
        size_t off = (size_t)(c0 + c) * Rs + r0 + a64;
        if (PERM) {
            int g32 = (a64 >> 5) * 32;
            int a = a64 & 31;
            ushort o8[8] __attribute__((aligned(16)));
            #pragma unroll
            for (int k = 0; k < 8; k++) {
                int pk = a + k;
                int rl = g32 + (pk >> 1) + ((pk & 1) << 4);
                int phys = ((rl >> 3) ^ g) * 8 + (rl & 7);
                o8[k] = tT[c * 72 + phys];
            }
            *(uint4*)(dst + off) = *(const uint4*)o8;
        } else {
            *(uint4*)(dst + off) = *(const uint4*)(tT + c * 72 + p * 8);
        }
    }
}

// ================= PREP0: {x->bf16 cvt | routing} (unchanged) =================
#define NB_CVT   ((TOK*DD)/8/256)           // 1536
#define NB_ROUTE (TOK/4)                    // 1024

__device__ __forceinline__ void cvt_body(const float* __restrict__ src, ushort* __restrict__ dst, int i) {
    const float4* s = ((const float4*)src) + (size_t)i * 2;
    float4 a = s[0], b = s[1];
    uint4 o;
    o.x = pk2(a.x, a.y); o.y = pk2(a.z, a.w);
    o.z = pk2(b.x, b.y); o.w = pk2(b.z, b.w);
    *(((uint4*)dst) + i) = o;
}

__device__ __forceinline__ void routing_body(
    const float* __restrict__ x, const float* __restrict__ v_w, const float* __restrict__ v_b,
    const float* __restrict__ gate_w, const float* __restrict__ gate_b,
    float* __restrict__ v_out, int* __restrict__ tok_e, float* __restrict__ tok_w, int blk)
{
    int wave = threadIdx.x >> 6, lane = threadIdx.x & 63;
    int t = blk * 4 + wave;
    const float* xr = x + (size_t)t * DD;
    float av = 0.f;
    float ag[8] = {0.f, 0.f, 0.f, 0.f, 0.f, 0.f, 0.f, 0.f};
    #pragma unroll
    for (int i = 0; i < 12; i++) {
        int d = lane + 64 * i;
        float xv = xr[d];
        av += xv * v_w[d];
        const float4* g = (const float4*)(gate_w + d * 8);
        float4 g0 = g[0], g1 = g[1];
        ag[0] += xv * g0.x; ag[1] += xv * g0.y; ag[2] += xv * g0.z; ag[3] += xv * g0.w;
        ag[4] += xv * g1.x; ag[5] += xv * g1.y; ag[6] += xv * g1.z; ag[7] += xv * g1.w;
    }
    #pragma unroll
    for (int off = 32; off >= 1; off >>= 1) {
        av += __shfl_xor(av, off);
        #pragma unroll
        for (int e = 0; e < 8; e++) ag[e] += __shfl_xor(ag[e], off);
    }
    if (lane == 0) {
        float vv = av + v_b[0];
        vv = fminf(fmaxf(vv, -3.f), 3.f);
        v_out[t] = vv;
        float lg[8];
        #pragma unroll
        for (int e = 0; e < 8; e++) lg[e] = ag[e] + gate_b[e];
        int e0 = 0;
        #pragma unroll
        for (int e = 1; e < 8; e++) if (lg[e] > lg[e0]) e0 = e;
        int e1 = -1;
        #pragma unroll
        for (int e = 0; e < 8; e++) if (e != e0 && (e1 < 0 || lg[e] > lg[e1])) e1 = e;
        float w0 = 1.f / (1.f + __expf(lg[e1] - lg[e0]));
        tok_e[2*t] = e0; tok_e[2*t+1] = e1;
        tok_w[2*t] = w0; tok_w[2*t+1] = 1.f - w0;
    }
}

__global__ __launch_bounds__(256) void prep0_kernel(
    const float* __restrict__ x, ushort* __restrict__ x_bf,
    const float* __restrict__ v_w, const float* __restrict__ v_b,
    const float* __restrict__ gate_w, const float* __restrict__ gate_b,
    float* __restrict__ v_out, int* __restrict__ tok_e, float* __restrict__ tok_w)
{
    int id = blockIdx.x;
    if (id < NB_CVT) { cvt_body(x, x_bf, id * 256 + threadIdx.x); return; }
    id -= NB_CVT;
    routing_body(x, v_w, v_b, gate_w, gate_b, v_out, tok_e, tok_w, id);
}

// ============ SETUP+BK+W1CVT (unchanged) ============
#define NB_W1T4  (12*48*EE/4)               // 1152 blocks x 4 tiles (1024 thr)

__device__ void setup_body(
    const int* __restrict__ tok_e, const float* __restrict__ tok_w,
    int* __restrict__ ctrl, int* __restrict__ row_token, float* __restrict__ row_w,
    int* __restrict__ slot)
{
    __shared__ int cnt[8], base[8], cursor[8];
    int tid = threadIdx.x;
    int lane = tid & 63;
    if (tid < 8) { cnt[tid] = 0; cursor[tid] = 0; }
    __syncthreads();

    int mye[8];
    #pragma unroll
    for (int it = 0; it < 8; it++) {
        int idx = it * 1024 + tid;
        int e = tok_e[idx];
        mye[it] = e;
        #pragma unroll
        for (int ex = 0; ex < 8; ex++) {
            unsigned long long m = __ballot(e == ex);
            if (e == ex && lane == (__ffsll((long long)m) - 1))
                atomicAdd(&cnt[ex], (int)__popcll(m));
        }
    }
    __syncthreads();
    if (tid == 0) {
        int b = 0;
        int* te = ctrl + 24;
        for (int i = 0; i < TILES; i++) te[i] = -1;
        #pragma unroll
        for (int e = 0; e < EE; e++) {
            base[e] = b;
            ctrl[16 + e] = b;
            int tiles = (cnt[e] + 127) >> 7;
            int t0 = b >> 7;
            for (int i = 0; i < tiles; i++) te[t0 + i] = e;
            b += tiles << 7;
        }
    }
    for (int p = tid; p < ROWS_CAP; p += 1024) row_token[p] = -1;
    __syncthreads();

    #pragma unroll
    for (int it = 0; it < 8; it++) {
        int idx = it * 1024 + tid;
        int e = mye[it];
        unsigned long long lt = (1ull << lane) - 1ull;
        int p = 0;
        #pragma unroll
        for (int ex = 0; ex < 8; ex++) {
            unsigned long long m = __ballot(e == ex);
            if (e == ex) {
                int leader = __ffsll((long long)m) - 1;
                int pos = (int)__popcll(m & lt);
                int bp = 0;
                if (lane == leader) bp = atomicAdd(&cursor[ex], (int)__popcll(m));
                bp = __shfl(bp, leader);
                p = base[ex] + bp + pos;
            }
        }
        row_token[p] = idx >> 1;
        row_w[p] = tok_w[idx];
        slot[idx] = p;
    }
}

__device__ void bk_body(int b, const float* __restrict__ v, float* __restrict__ feats) {
    int t = threadIdx.x;
    bool act = t < 256;
    __shared__ float sm[256][8];
    const mob I = {{1.f,0.f},{0.f,0.f},{0.f,0.f},{1.f,0.f}};
    cplx a[8];
    const float* vb = v + (size_t)b * NN;
    if (act) {
        #pragma unroll
        for (int j = 0; j < 8; j++) { a[j].x = -2.f + vb[t*8 + j]; a[j].y = -1.f; }
    }

    mob cur = I;
    if (act) {
        #pragma unroll
        for (int j = 0; j < 8; j++) cur = mstep(a[j], cur);
        mnorm(cur);
        mstore(sm[t], cur);
    }
    for (int s = 1; s < 256; s <<= 1) {
        __syncthreads();
        mob prev; bool has = act && (t >= s);
        if (has) prev = mload(sm[t - s]);
        __syncthreads();
        if (has) { cur = mmul(cur, prev); mnorm(cur); mstore(sm[t], cur); }
    }
    __syncthreads();
    cplx dreg[8];
    if (act) {
        mob P = (t > 0) ? mload(sm[t - 1]) : I;
        #pragma unroll
        for (int j = 0; j < 8; j++) {
            P = mstep(a[j], P); mnorm(P);
            dreg[j] = cdivc(P.m00, P.m10);
        }
    }
    __syncthreads();

    cur = I;
    if (act) {
        #pragma unroll
        for (int j = 7; j >= 0; j--) cur = mstep(a[j], cur);
        mnorm(cur);
        mstore(sm[t], cur);
    }
    for (int s = 1; s < 256; s <<= 1) {
        __syncthreads();
        mob nxt; bool has = act && (t + s < 256);
        if (has) nxt = mload(sm[t + s]);
        __syncthreads();
        if (has) { cur = mmul(cur, nxt); mnorm(cur); mstore(sm[t], cur); }
    }
    __syncthreads();
    if (act) {
        mob P = (t < 255) ? mload(sm[t + 1]) : I;
        #pragma unroll
        for (int j = 7; j >= 0; j--) {
            P = mstep(a[j], P); mnorm(P);
            cplx e = cdivc(P.m00, P.m10);
            cplx den = {dreg[j].x + e.x - a[j].x, dreg[j].y + e.y - a[j].y};
            cplx one = {1.f, 0.f};
            cplx G = cdivc(one, den);
            int i = b * NN + t*8 + j;
            feats[2*i]   = G.x;
            feats[2*i+1] = G.y;
        }
    }
}

__global__ __launch_bounds__(1024) void setup_bk_kernel(
    const int* __restrict__ tok_e, const float* __restrict__ tok_w,
    int* __restrict__ ctrl, int* __restrict__ row_token, float* __restrict__ row_w,
    int* __restrict__ slot, const float* __restrict__ v, float* __restrict__ feats,
    const float* __restrict__ w1, ushort* __restrict__ w1t)
{
    if (blockIdx.x == 0) { setup_body(tok_e, tok_w, ctrl, row_token, row_w, slot); return; }
    if (blockIdx.x <= BB) { bk_body(blockIdx.x - 1, v, feats); return; }
    __shared__ __align__(16) ushort tT4[4 * 4608];
    int tt = (blockIdx.x - 1 - BB) * 4 + (threadIdx.x >> 8);
    int e = tt / (12 * 48);
    int rem = tt - e * 12 * 48;
    int cy = rem / 12;
    int rx = rem - cy * 12;
    tcvt64_body<false>(w1 + (size_t)e * DD * FF, w1t + (size_t)e * FF * DD,
                       DD, FF, rx * 64, cy * 64,
                       tT4 + (threadIdx.x >> 8) * 4608, threadIdx.x & 255);
}

#define MFMAS() do { \
        _Pragma("unroll") \
        for (int i = 0; i < 4; i++) \
            _Pragma("unroll") \
            for (int j = 0; j < 4; j++) \
                acc[i][j] = __builtin_amdgcn_mfma_f32_16x16x32_bf16(afr[i], bfr[j], acc[i][j], 0, 0, 0); \
    } while (0)

// ---------- K5-fused: NEW 8-phase-style gemm1 (T3+T4 template) + w2cvt tail ----------
// gemm1: BM=128 (single expert/tile), BN=256, BK=64, 8 waves (2Mx4N, 64x64/wave).
// THREE LDS slots (A 16KB + B 32KB each = 144KB): stage(kt+2) issued during tile
// kt's two phases -> 2 K-tiles (4 phases) of slack; steady-state wait is
// vmcnt(6) (= one tile's 6 gloads outstanding), NEVER draining young loads.
// Per phase: {1 stage-unit || 8 ds_read_b128 -> lgkmcnt(0) -> 16 MFMA -> barrier}:
// 2 barriers/K64 (round 9 had 4), 16 MFMA/barrier. Slot ledger:
//   slot(kt)=kt%3; stage(kt+2)->slot(kt-1), whose reads sealed at kt-1's end
//   barrier; vmcnt at kt's end ensures stage(kt+1) visible after the barrier.
// XCD map: bid=8s+x -> XCD x gets tiles x*9..x*9+8 for each fx run ->
// per-XCD working set (4 B-panels + 9 A-tiles ~ 3.4MB) fits its 4MB L2.
#define G1N   (72 * 12)                 // 864 gemm1 blocks
#define NW2T  (48 * 12 * EE / 2)        // 2304 w2cvt blocks (2 tiles ea)

__global__ __launch_bounds__(512, 2) void gemm1_fused_kernel(
    const ushort* __restrict__ x_bf, const ushort* __restrict__ w1t, const float* __restrict__ b1,
    const int* __restrict__ ctrl, const int* __restrict__ row_token, ushort* __restrict__ H,
    const float* __restrict__ w2, ushort* __restrict__ w2t)
{
    __shared__ __align__(16) ushort SH[73728];     // 144KB: A3 [3][128*64] + B3 [3][256*64]
    __shared__ int toks[128];
    int bid = blockIdx.x;
    int tid = threadIdx.x;

    if (bid >= G1N) {
        // ---- w2 [e][3072][768] -> w2t [e][768][3072] with f-perm; 2 tiles/block ----
        int tt = (bid - G1N) * 2 + (tid >> 8);
        int e = tt / (48 * 12);
        int rem = tt - e * 48 * 12;
        int cy = rem / 48;
        int rx = rem - cy * 48;
        ushort* tT = SH + (tid >> 8) * 4608;
        tcvt64_body<true>(w2 + (size_t)e * FF * DD, w2t + (size_t)e * DD * FF,
                          FF, DD, rx * 64, cy * 64, tT, tid & 255);
        return;
    }

    // XCD-affine remap: bid = 8*s + x; fx = s/9, tile = x*9 + s%9 (864 = 8*108)
    int x = bid & 7, s = bid >> 3;
    int fx = s / 9;
    int tile = x * 9 + (s - fx * 9);
    int e = ctrl[24 + tile];
    if (e < 0) return;
    int p0 = tile * 128;
    int f0 = fx * 256;

    ushort* B3 = SH + 3 * 8192;        // B slots base (3 x 16384 ushorts)

    if (tid < 128) { int tk = row_token[p0 + tid]; toks[tid] = tk < 0 ? 0 : tk; }
    __syncthreads();

    int wave = tid >> 6, lane = tid & 63;
    int wr = wave >> 2, wc = wave & 3;           // 2M x 4N wave grid
    int w16 = wave * 16;

    // ---- stage-side addressing (8 rows per gload, 8 lanes/row, 128B rows) ----
    int srow = lane >> 3;                         // 0..7
    int kq = ((lane & 7) ^ srow) * 8;             // swizzled global k-quad (ushorts)
    int tokA0 = toks[w16 + srow];
    int tokA1 = toks[w16 + 8 + srow];
    const ushort* aA0 = x_bf + (size_t)tokA0 * DD + kq;
    const ushort* aA1 = x_bf + (size_t)tokA1 * DD + kq;
    const ushort* w1e = w1t + (size_t)e * (FF * DD);
    const ushort* bB00 = w1e + (size_t)(f0 +       w16 + srow) * DD + kq;
    const ushort* bB01 = w1e + (size_t)(f0 +       w16 + 8 + srow) * DD + kq;
    const ushort* bB10 = w1e + (size_t)(f0 + 128 + w16 + srow) * DD + kq;
    const ushort* bB11 = w1e + (size_t)(f0 + 128 + w16 + 8 + srow) * DD + kq;
    int dA0 = w16 * 64;                           // LDS dest (ushort idx), linear
    int dA1 = dA0 + 512;

    // ---- read-side addressing ----
    int lm = lane & 15, q = lane >> 4;
    int qa0 = ((q    ) ^ (lm & 7)) * 8;           // khalf0 swizzled quad
    int qa1 = ((q | 4) ^ (lm & 7)) * 8;           // khalf1
    int arow = (wr * 64 + lm) * 64;               // + i*1024
    int brow = (wc * 64 + lm) * 64;               // + j*1024

    floatx4 zero4 = {0.f, 0.f, 0.f, 0.f};
    floatx4 acc[4][4];
    #pragma unroll
    for (int i = 0; i < 4; i++)
        #pragma unroll
        for (int j = 0; j < 4; j++) acc[i][j] = zero4;

    #define STG_A(SL, kt) do { \
        gload16(aA0 + (kt)*64, SH + (SL)*8192 + dA0); \
        gload16(aA1 + (kt)*64, SH + (SL)*8192 + dA1); } while (0)
    #define STG_B(SL, kt) do { \
        gload16(bB00 + (kt)*64, B3 + (SL)*16384 + dA0); \
        gload16(bB01 + (kt)*64, B3 + (SL)*16384 + dA1); \
        gload16(bB10 + (kt)*64, B3 + (SL)*16384 + 8192 + dA0); \
        gload16(bB11 + (kt)*64, B3 + (SL)*16384 + 8192 + dA1); } while (0)

    #define G1_PHASE(SL, QH) do { \
        bf16x8 afr[4], bfr[4]; \
        _Pragma("unroll") \
        for (int i = 0; i < 4; i++) \
            afr[i] = *(const bf16x8*)(const void*)(SH + (SL)*8192 + arow + i*1024 + (QH)); \
        _Pragma("unroll") \
        for (int j = 0; j < 4; j++) \
            bfr[j] = *(const bf16x8*)(const void*)(B3 + (SL)*16384 + brow + j*1024 + (QH)); \
        asm volatile("s_waitcnt lgkmcnt(0)" ::: "memory"); \
        __builtin_amdgcn_sched_barrier(0); \
        __builtin_amdgcn_s_setprio(1); \
        MFMAS(); \
        __builtin_amdgcn_s_setprio(0); } while (0)

    // tile kt: phase A (khalf0, stage A-unit of kt+2) ; phase B (khalf1, stage
    // B-units of kt+2, then vmcnt ensuring stage(kt+1) before the end barrier).
    #define G1_TILE(kt, SL, S2) do { \
        bool st_ = (kt) < 10; \
        if (st_) STG_A(S2, (kt) + 2); \
        G1_PHASE(SL, qa0); \
        __builtin_amdgcn_s_barrier(); \
        if (st_) STG_B(S2, (kt) + 2); \
        G1_PHASE(SL, qa1); \
        if (st_)            { asm volatile("s_waitcnt vmcnt(6)" ::: "memory"); } \
        else if ((kt) < 11) { asm volatile("s_waitcnt vmcnt(0)" ::: "memory"); } \
        __builtin_amdgcn_s_barrier(); } while (0)

    // prologue: tiles 0,1 staged (12 gloads); wait stage(0) done (6 outstanding)
    STG_A(0, 0); STG_B(0, 0);
    STG_A(1, 1); STG_B(1, 1);
    asm volatile("s_waitcnt vmcnt(6)" ::: "memory");
    __builtin_amdgcn_s_barrier();

    for (int kb = 0; kb < 12; kb += 3) {
        G1_TILE(kb    , 0, 2);
        G1_TILE(kb + 1, 1, 0);
        G1_TILE(kb + 2, 2, 1);
    }
    #undef G1_TILE
    #undef G1_PHASE
    #undef STG_B
    #undef STG_A

    // epilogue: paired u32 stores at permuted positions f0+wc*64+jp*32+lm*2
    #pragma unroll
    for (int i = 0; i < 4; i++) {
        #pragma unroll
        for (int jp = 0; jp < 2; jp++) {
            float bias0 = b1[e * FF + f0 + wc*64 + (2*jp)*16 + lm];
            float bias1 = b1[e * FF + f0 + wc*64 + (2*jp+1)*16 + lm];
            #pragma unroll
            for (int r = 0; r < 4; r++) {
                int m = wr*64 + i*16 + q*4 + r;
                float h0 = gelu_f(acc[i][2*jp][r] + bias0);
                float h1 = gelu_f(acc[i][2*jp+1][r] + bias1);
                *(unsigned int*)(H + (size_t)(p0 + m) * FF + f0 + wc*64 + jp*32 + lm*2) = pk2(h0, h1);
            }
        }
    }
}

// ---------- K6: GEMM2 (unchanged) ----------
#define STAGE64(AW, BW, k0) do { \
        _Pragma("unroll") \
        for (int g = 0; g < 4; g++) { \
            gload16(ag[g] + (k0), (AW) + g*8*64); \
            gload16(bg[g] + (k0), (BW) + g*8*64); \
        } } while (0)

#define LOADFR64(APTR, BPTR, QX) do { \
        _Pragma("unroll") \
        for (int i = 0; i < 4; i++) \
            afr[i] = *(const bf16x8*)(const void*)((APTR) + (wm + i*16 + lm) * 64 + (QX)); \
        _Pragma("unroll") \
        for (int j = 0; j < 4; j++) \
            bfr[j] = *(const bf16x8*)(const void*)((BPTR) + (wn + j*16 + lm) * 64 + (QX)); \
    } while (0)

#define PIPE64(NK) do { \
    STAGE64(AsW0, BsW0, 0); \
    STAGE64(AsW1, BsW1, 64); \
    for (int ks = 0; ks < (NK); ks++) { \
        int cur = ks & 1; \
        const ushort* Ab = cur ? As[1] : As[0]; \
        const ushort* Bb = cur ? Bs[1] : Bs[0]; \
        ushort* AsN = cur ? AsW1 : AsW0; \
        ushort* BsN = cur ? BsW1 : BsW0; \
        if (ks < (NK) - 1) { asm volatile("s_waitcnt vmcnt(8)" ::: "memory"); } \
        else               { asm volatile("s_waitcnt vmcnt(0)" ::: "memory"); } \
        __builtin_amdgcn_s_barrier(); \
        { \
            bf16x8 afr[4], bfr[4]; \
            LOADFR64(Ab, Bb, qx0); \
            __builtin_amdgcn_s_setprio(1); \
            MFMAS(); \
            __builtin_amdgcn_s_setprio(0); \
        } \
        { \
            bf16x8 afr[4], bfr[4]; \
            LOADFR64(Ab, Bb, qx0 ^ 32); \
            asm volatile("s_waitcnt lgkmcnt(0)" ::: "memory"); \
            __builtin_amdgcn_sched_barrier(0); \
            __builtin_amdgcn_s_barrier(); \
            if (ks + 2 < (NK)) STAGE64(AsN, BsN, ks*64 + 128); \
            __builtin_amdgcn_s_setprio(1); \
            MFMAS(); \
            __builtin_amdgcn_s_setprio(0); \
        } \
    } } while (0)

__global__ __launch_bounds__(256) void gemm2_kernel(
    const ushort* __restrict__ H, const ushort* __restrict__ w2t, const float* __restrict__ b2,
    const int* __restrict__ ctrl, const float* __restrict__ row_w, float* __restrict__ Y)
{
    int tile = blockIdx.x;
    int e = ctrl[24 + tile];
    if (e < 0) return;
    int p0 = tile * 128;
    int d0 = blockIdx.y * 128;

    __shared__ ushort As[2][128 * 64];
    __shared__ ushort Bs[2][128 * 64];

    int tid = threadIdx.x;
    int wave = tid >> 6, lane = tid & 63;
    int srow = lane >> 3;
    int kq = (((lane & 7) ^ (srow & 7))) * 8;
    const ushort* ag[4];
    #pragma unroll
    for (int g = 0; g < 4; g++)
        ag[g] = H + (size_t)(p0 + wave*32 + g*8 + srow) * FF + kq;
    const ushort* w2e = w2t + (size_t)e * (DD * FF);
    const ushort* bg[4];
    #pragma unroll
    for (int g = 0; g < 4; g++)
        bg[g] = w2e + (size_t)(d0 + wave*32 + g*8 + srow) * FF + kq;
    ushort* AsW0 = &As[0][wave * 32 * 64];
    ushort* BsW0 = &Bs[0][wave * 32 * 64];
    ushort* AsW1 = &As[1][wave * 32 * 64];
    ushort* BsW1 = &Bs[1][wave * 32 * 64];

    floatx4 zero4 = {0.f, 0.f, 0.f, 0.f};
    floatx4 acc[4][4];
    #pragma unroll
    for (int i = 0; i < 4; i++)
        #pragma unroll
        for (int j = 0; j < 4; j++) acc[i][j] = zero4;

    int wm = (wave & 1) * 64, wn = (wave >> 1) * 64;
    int lm = lane & 15, q = lane >> 4;
    int qx0 = (q ^ (lm & 7)) * 8;

    PIPE64(FF/64);

    #pragma unroll
    for (int i = 0; i < 4; i++) {
        #pragma unroll
        for (int j = 0; j < 4; j++) {
            int n = wn + j*16 + lm;
            float bias = b2[e * DD + d0 + n];
            #pragma unroll
            for (int r = 0; r < 4; r++) {
                int m = wm + i*16 + q*4 + r;
                float wgt = row_w[p0 + m];
                Y[(size_t)(p0 + m) * DD + d0 + n] = wgt * (acc[i][j][r] + bias);
            }
        }
    }
}

// ---------- K7: final combine (unchanged) ----------
__global__ __launch_bounds__(256) void final_kernel(
    const float* __restrict__ Y, const int* __restrict__ slot, const float* __restrict__ feats,
    const float* __restrict__ out_w, const float* __restrict__ out_b,
    const float* __restrict__ bk_scale, float* __restrict__ out)
{
    int idx = blockIdx.x * 256 + threadIdx.x;
    int base = idx * 4;
    int t = base / DD;
    int d = base - t * DD;
    int p0 = slot[2*t], p1 = slot[2*t + 1];
    const float4 ya = *(const float4*)(Y + (size_t)p0 * DD + d);
    const float4 yb = *(const float4*)(Y + (size_t)p1 * DD + d);
    float f0 = feats[2*t], f1 = feats[2*t + 1];
    f0 = fminf(fmaxf(f0, -10.f), 10.f);
    f1 = fminf(fmaxf(f1, -10.f), 10.f);
    float ff[4] = {ya.x + yb.x, ya.y + yb.y, ya.z + yb.z, ya.w + yb.w};
    float4 o;
    float* op = (float*)&o;
    #pragma unroll
    for (int u = 0; u < 4; u++) {
        float spec = f0 * out_w[d + u] + f1 * out_w[DD + d + u] + out_b[d + u];
        op[u] = ff[u] + bk_scale[d + u] * spec;
    }
    *(float4*)(out + base) = o;
}

extern "C" void kernel_launch(void* const* d_in, const int* in_sizes, int n_in,
                              void* d_out, int out_size, void* d_ws, size_t ws_size,
                              hipStream_t stream)
{
    const float* x      = (const float*)d_in[0];
    const float* v_w    = (const float*)d_in[1];
    const float* v_b    = (const float*)d_in[2];
    const float* gate_w = (const float*)d_in[3];
    const float* gate_b = (const float*)d_in[4];
    const float* w1     = (const float*)d_in[5];
    const float* b1     = (const float*)d_in[6];
    const float* w2     = (const float*)d_in[7];
    const float* b2     = (const float*)d_in[8];
    const float* out_w  = (const float*)d_in[9];
    const float* out_b  = (const float*)d_in[10];
    const float* bk_s   = (const float*)d_in[11];

    char* ws = (char*)d_ws;
    int*    ctrl    = (int*)(ws + OFF_CTRL);
    float*  v       = (float*)(ws + OFF_V);
    int*    tok_e   = (int*)(ws + OFF_TOKE);
    float*  tok_w   = (float*)(ws + OFF_TOKW);
    int*    row_tok = (int*)(ws + OFF_ROWTOK);
    float*  row_w   = (float*)(ws + OFF_ROWW);
    int*    slot    = (int*)(ws + OFF_SLOT);
    float*  feats   = (float*)(ws + OFF_FEATS);
    ushort* w2t     = (ushort*)(ws + OFF_W2T);
    ushort* x_bf    = (ushort*)(ws + OFF_XBF);
    ushort* w1t     = (ushort*)(ws + OFF_W1T);
    ushort* H       = (ushort*)(ws + OFF_H);
    float*  Y       = (float*)(ws + OFF_Y);
    float*  out     = (float*)d_out;

    prep0_kernel<<<NB_CVT + NB_ROUTE, 256, 0, stream>>>(
        x, x_bf, v_w, v_b, gate_w, gate_b, v, tok_e, tok_w);
    setup_bk_kernel<<<1 + BB + NB_W1T4, 1024, 0, stream>>>(
        tok_e, tok_w, ctrl, row_tok, row_w, slot, v, feats, w1, w1t);
    gemm1_fused_kernel<<<G1N + NW2T, 512, 0, stream>>>(x_bf, w1t, b1, ctrl, row_tok, H, w2, w2t);
    gemm2_kernel<<<dim3(TILES, DD / 128), 256, 0, stream>>>(H, w2t, b2, ctrl, row_w, Y);
    final_kernel<<<(TOK * DD) / 1024, 256, 0, stream>>>(Y, slot, feats, out_w, out_b, bk_s, out);
}

// Round 12
// 182.793 us; speedup vs baseline: 1.1385x; 1.1385x over previous
//
#include <hip/hip_runtime.h>
#include <hip/hip_bf16.h>

#define BB 2
#define NN 2048
#define DD 768
#define EE 8
#define FF 3072
#define TOK (BB*NN)       // 4096
#define ROWS_CAP 9216
#define TILES 72

typedef __attribute__((ext_vector_type(8))) __bf16 bf16x8;
typedef __attribute__((ext_vector_type(4))) float floatx4;

// ---------- ws layout (bytes) ----------
#define OFF_CTRL    0ull
#define OFF_V       1024ull
#define OFF_TOKE    17408ull
#define OFF_TOKW    50176ull
#define OFF_ROWTOK  82944ull
#define OFF_ROWW    119808ull
#define OFF_SLOT    156672ull
#define OFF_FEATS   189440ull
#define OFF_W2T     222208ull               // ushort[8*768*3072] (w2^T: [e][d][f'], f' perm)
#define OFF_XBF     37970944ull             // ushort[4096*768]
#define OFF_W1T     44262400ull             // ushort[8*3072*768] (w1^T: [e][f][d])
#define OFF_H       82011136ull             // ushort[9216*3072]  (f' perm layout)
#define OFF_Y       OFF_XBF                 // float[9216*768], aliases dead XBF+W1T

__device__ __forceinline__ ushort f2b(float f) {
    union { float f; unsigned int i; } v; v.f = f;
    unsigned int u = v.i;
    unsigned int r = (u + 0x7FFFu + ((u >> 16) & 1u)) >> 16;
    return (ushort)r;
}
__device__ __forceinline__ unsigned int pk2(float lo, float hi) {
    union { float f; unsigned int u; } a, b;
    a.f = lo; b.f = hi;
    unsigned int ra = ((a.u + 0x7FFFu + ((a.u >> 16) & 1u)) >> 16) & 0xFFFFu;
    unsigned int rb = (b.u + 0x7FFFu + ((b.u >> 16) & 1u)) & 0xFFFF0000u;
    return ra | rb;
}
__device__ __forceinline__ float gelu_f(float x) {
    float z = 0.7978845608028654f * x * (1.f + 0.044715f * x * x);
    z = fminf(fmaxf(z, -12.f), 12.f);
    float e = __expf(2.f * z);
    return 0.5f * x * (1.f + (e - 1.f) / (e + 1.f));
}
__device__ __forceinline__ void gload16(const ushort* g, ushort* l) {
    __builtin_amdgcn_global_load_lds((const __attribute__((address_space(1))) void*)g,
                                     (__attribute__((address_space(3))) void*)l,
                                     16, 0, 0);
}

// ---------- complex / Mobius helpers ----------
struct cplx { float x, y; };
__device__ __forceinline__ cplx cmulc(cplx a, cplx b) { return {a.x*b.x - a.y*b.y, a.x*b.y + a.y*b.x}; }
__device__ __forceinline__ cplx caddc(cplx a, cplx b) { return {a.x + b.x, a.y + b.y}; }
__device__ __forceinline__ cplx cdivc(cplx a, cplx b) {
    float s = 1.f / (b.x*b.x + b.y*b.y);
    return {(a.x*b.x + a.y*b.y)*s, (a.y*b.x - a.x*b.y)*s};
}
struct mob { cplx m00, m01, m10, m11; };
__device__ __forceinline__ mob mmul(const mob& A, const mob& B) {
    mob C;
    C.m00 = caddc(cmulc(A.m00, B.m00), cmulc(A.m01, B.m10));
    C.m01 = caddc(cmulc(A.m00, B.m01), cmulc(A.m01, B.m11));
    C.m10 = caddc(cmulc(A.m10, B.m00), cmulc(A.m11, B.m10));
    C.m11 = caddc(cmulc(A.m10, B.m01), cmulc(A.m11, B.m11));
    return C;
}
__device__ __forceinline__ void mnorm(mob& A) {
    float s = fabsf(A.m00.x);
    s = fmaxf(s, fabsf(A.m00.y)); s = fmaxf(s, fabsf(A.m01.x)); s = fmaxf(s, fabsf(A.m01.y));
    s = fmaxf(s, fabsf(A.m10.x)); s = fmaxf(s, fabsf(A.m10.y)); s = fmaxf(s, fabsf(A.m11.x));
    s = fmaxf(s, fabsf(A.m11.y));
    float r = 1.f / fmaxf(s, 1e-30f);
    A.m00.x *= r; A.m00.y *= r; A.m01.x *= r; A.m01.y *= r;
    A.m10.x *= r; A.m10.y *= r; A.m11.x *= r; A.m11.y *= r;
}
__device__ __forceinline__ mob mstep(cplx a, const mob& P) {
    mob C;
    C.m00 = {a.x*P.m00.x - a.y*P.m00.y - P.m10.x, a.x*P.m00.y + a.y*P.m00.x - P.m10.y};
    C.m01 = {a.x*P.m01.x - a.y*P.m01.y - P.m11.x, a.x*P.m01.y + a.y*P.m01.x - P.m11.y};
    C.m10 = P.m00; C.m11 = P.m01;
    return C;
}
__device__ __forceinline__ void mstore(float* s, const mob& A) {
    s[0]=A.m00.x; s[1]=A.m00.y; s[2]=A.m01.x; s[3]=A.m01.y;
    s[4]=A.m10.x; s[5]=A.m10.y; s[6]=A.m11.x; s[7]=A.m11.y;
}
__device__ __forceinline__ mob mload(const float* s) {
    mob A;
    A.m00 = {s[0], s[1]}; A.m01 = {s[2], s[3]};
    A.m10 = {s[4], s[5]}; A.m11 = {s[6], s[7]};
    return A;
}

// ============ 64x64 transpose-convert (unchanged, round 8 swizzle) ============
template<bool PERM>
__device__ __forceinline__ void tcvt64_body(
    const float* __restrict__ src, ushort* __restrict__ dst,
    int Rs, int Cs, int r0, int c0, ushort* __restrict__ tT /* [64*72] */, int tid)
{
    int lr = tid >> 2;
    int lc0 = (tid & 3) * 16;
    const float* sp = src + (size_t)(r0 + lr) * Cs + c0 + lc0;
    float4 v[4];
    #pragma unroll
    for (int u = 0; u < 4; u++) v[u] = *(const float4*)(sp + 4*u);
    int chw = lr >> 3, wbit = lr & 7;
    #pragma unroll
    for (int u = 0; u < 4; u++) {
        float vs[4] = {v[u].x, v[u].y, v[u].z, v[u].w};
        #pragma unroll
        for (int e2 = 0; e2 < 4; e2++) {
            int col = lc0 + 4*u + e2;
            int g = (col >> 4) & 3;
            tT[col * 72 + ((chw ^ g) << 3) + wbit] = f2b(vs[e2]);
        }
    }
    __syncthreads();
    int p = tid & 7;
    #pragma unroll
    for (int pass = 0; pass < 2; pass++) {
        int c = (tid >> 3) + pass * 32;
        int g = (c >> 4) & 3;
        int chl = p ^ g;
        int a64 = chl * 8;
        size_t off = (size_t)(c0 + c) * Rs + r0 + a64;
        if (PERM) {
            int g32 = (a64 >> 5) * 32;
            int a = a64 & 31;
            ushort o8[8] __attribute__((aligned(16)));
            #pragma unroll
            for (int k = 0; k < 8; k++) {
                int pk = a + k;
                int rl = g32 + (pk >> 1) + ((pk & 1) << 4);
                int phys = ((rl >> 3) ^ g) * 8 + (rl & 7);
                o8[k] = tT[c * 72 + phys];
            }
            *(uint4*)(dst + off) = *(const uint4*)o8;
        } else {
            *(uint4*)(dst + off) = *(const uint4*)(tT + c * 72 + p * 8);
        }
    }
}

// ================= PREP0: {x->bf16 cvt | routing} (unchanged) =================
#define NB_CVT   ((TOK*DD)/8/256)           // 1536
#define NB_ROUTE (TOK/4)                    // 1024

__device__ __forceinline__ void cvt_body(const float* __restrict__ src, ushort* __restrict__ dst, int i) {
    const float4* s = ((const float4*)src) + (size_t)i * 2;
    float4 a = s[0], b = s[1];
    uint4 o;
    o.x = pk2(a.x, a.y); o.y = pk2(a.z, a.w);
    o.z = pk2(b.x, b.y); o.w = pk2(b.z, b.w);
    *(((uint4*)dst) + i) = o;
}

__device__ __forceinline__ void routing_body(
    const float* __restrict__ x, const float* __restrict__ v_w, const float* __restrict__ v_b,
    const float* __restrict__ gate_w, const float* __restrict__ gate_b,
    float* __restrict__ v_out, int* __restrict__ tok_e, float* __restrict__ tok_w, int blk)
{
    int wave = threadIdx.x >> 6, lane = threadIdx.x & 63;
    int t = blk * 4 + wave;
    const float* xr = x + (size_t)t * DD;
    float av = 0.f;
    float ag[8] = {0.f, 0.f, 0.f, 0.f, 0.f, 0.f, 0.f, 0.f};
    #pragma unroll
    for (int i = 0; i < 12; i++) {
        int d = lane + 64 * i;
        float xv = xr[d];
        av += xv * v_w[d];
        const float4* g = (const float4*)(gate_w + d * 8);
        float4 g0 = g[0], g1 = g[1];
        ag[0] += xv * g0.x; ag[1] += xv * g0.y; ag[2] += xv * g0.z; ag[3] += xv * g0.w;
        ag[4] += xv * g1.x; ag[5] += xv * g1.y; ag[6] += xv * g1.z; ag[7] += xv * g1.w;
    }
    #pragma unroll
    for (int off = 32; off >= 1; off >>= 1) {
        av += __shfl_xor(av, off);
        #pragma unroll
        for (int e = 0; e < 8; e++) ag[e] += __shfl_xor(ag[e], off);
    }
    if (lane == 0) {
        float vv = av + v_b[0];
        vv = fminf(fmaxf(vv, -3.f), 3.f);
        v_out[t] = vv;
        float lg[8];
        #pragma unroll
        for (int e = 0; e < 8; e++) lg[e] = ag[e] + gate_b[e];
        int e0 = 0;
        #pragma unroll
        for (int e = 1; e < 8; e++) if (lg[e] > lg[e0]) e0 = e;
        int e1 = -1;
        #pragma unroll
        for (int e = 0; e < 8; e++) if (e != e0 && (e1 < 0 || lg[e] > lg[e1])) e1 = e;
        float w0 = 1.f / (1.f + __expf(lg[e1] - lg[e0]));
        tok_e[2*t] = e0; tok_e[2*t+1] = e1;
        tok_w[2*t] = w0; tok_w[2*t+1] = 1.f - w0;
    }
}

__global__ __launch_bounds__(256) void prep0_kernel(
    const float* __restrict__ x, ushort* __restrict__ x_bf,
    const float* __restrict__ v_w, const float* __restrict__ v_b,
    const float* __restrict__ gate_w, const float* __restrict__ gate_b,
    float* __restrict__ v_out, int* __restrict__ tok_e, float* __restrict__ tok_w)
{
    int id = blockIdx.x;
    if (id < NB_CVT) { cvt_body(x, x_bf, id * 256 + threadIdx.x); return; }
    id -= NB_CVT;
    routing_body(x, v_w, v_b, gate_w, gate_b, v_out, tok_e, tok_w, id);
}

// ============ SETUP+BK+W1CVT (unchanged) ============
#define NB_W1T4  (12*48*EE/4)               // 1152 blocks x 4 tiles (1024 thr)

__device__ void setup_body(
    const int* __restrict__ tok_e, const float* __restrict__ tok_w,
    int* __restrict__ ctrl, int* __restrict__ row_token, float* __restrict__ row_w,
    int* __restrict__ slot)
{
    __shared__ int cnt[8], base[8], cursor[8];
    int tid = threadIdx.x;
    int lane = tid & 63;
    if (tid < 8) { cnt[tid] = 0; cursor[tid] = 0; }
    __syncthreads();

    int mye[8];
    #pragma unroll
    for (int it = 0; it < 8; it++) {
        int idx = it * 1024 + tid;
        int e = tok_e[idx];
        mye[it] = e;
        #pragma unroll
        for (int ex = 0; ex < 8; ex++) {
            unsigned long long m = __ballot(e == ex);
            if (e == ex && lane == (__ffsll((long long)m) - 1))
                atomicAdd(&cnt[ex], (int)__popcll(m));
        }
    }
    __syncthreads();
    if (tid == 0) {
        int b = 0;
        int* te = ctrl + 24;
        for (int i = 0; i < TILES; i++) te[i] = -1;
        #pragma unroll
        for (int e = 0; e < EE; e++) {
            base[e] = b;
            ctrl[16 + e] = b;
            int tiles = (cnt[e] + 127) >> 7;
            int t0 = b >> 7;
            for (int i = 0; i < tiles; i++) te[t0 + i] = e;
            b += tiles << 7;
        }
    }
    for (int p = tid; p < ROWS_CAP; p += 1024) row_token[p] = -1;
    __syncthreads();

    #pragma unroll
    for (int it = 0; it < 8; it++) {
        int idx = it * 1024 + tid;
        int e = mye[it];
        unsigned long long lt = (1ull << lane) - 1ull;
        int p = 0;
        #pragma unroll
        for (int ex = 0; ex < 8; ex++) {
            unsigned long long m = __ballot(e == ex);
            if (e == ex) {
                int leader = __ffsll((long long)m) - 1;
                int pos = (int)__popcll(m & lt);
                int bp = 0;
                if (lane == leader) bp = atomicAdd(&cursor[ex], (int)__popcll(m));
                bp = __shfl(bp, leader);
                p = base[ex] + bp + pos;
            }
        }
        row_token[p] = idx >> 1;
        row_w[p] = tok_w[idx];
        slot[idx] = p;
    }
}

__device__ void bk_body(int b, const float* __restrict__ v, float* __restrict__ feats) {
    int t = threadIdx.x;
    bool act = t < 256;
    __shared__ float sm[256][8];
    const mob I = {{1.f,0.f},{0.f,0.f},{0.f,0.f},{1.f,0.f}};
    cplx a[8];
    const float* vb = v + (size_t)b * NN;
    if (act) {
        #pragma unroll
        for (int j = 0; j < 8; j++) { a[j].x = -2.f + vb[t*8 + j]; a[j].y = -1.f; }
    }

    mob cur = I;
    if (act) {
        #pragma unroll
        for (int j = 0; j < 8; j++) cur = mstep(a[j], cur);
        mnorm(cur);
        mstore(sm[t], cur);
    }
    for (int s = 1; s < 256; s <<= 1) {
        __syncthreads();
        mob prev; bool has = act && (t >= s);
        if (has) prev = mload(sm[t - s]);
        __syncthreads();
        if (has) { cur = mmul(cur, prev); mnorm(cur); mstore(sm[t], cur); }
    }
    __syncthreads();
    cplx dreg[8];
    if (act) {
        mob P = (t > 0) ? mload(sm[t - 1]) : I;
        #pragma unroll
        for (int j = 0; j < 8; j++) {
            P = mstep(a[j], P); mnorm(P);
            dreg[j] = cdivc(P.m00, P.m10);
        }
    }
    __syncthreads();

    cur = I;
    if (act) {
        #pragma unroll
        for (int j = 7; j >= 0; j--) cur = mstep(a[j], cur);
        mnorm(cur);
        mstore(sm[t], cur);
    }
    for (int s = 1; s < 256; s <<= 1) {
        __syncthreads();
        mob nxt; bool has = act && (t + s < 256);
        if (has) nxt = mload(sm[t + s]);
        __syncthreads();
        if (has) { cur = mmul(cur, nxt); mnorm(cur); mstore(sm[t], cur); }
    }
    __syncthreads();
    if (act) {
        mob P = (t < 255) ? mload(sm[t + 1]) : I;
        #pragma unroll
        for (int j = 7; j >= 0; j--) {
            P = mstep(a[j], P); mnorm(P);
            cplx e = cdivc(P.m00, P.m10);
            cplx den = {dreg[j].x + e.x - a[j].x, dreg[j].y + e.y - a[j].y};
            cplx one = {1.f, 0.f};
            cplx G = cdivc(one, den);
            int i = b * NN + t*8 + j;
            feats[2*i]   = G.x;
            feats[2*i+1] = G.y;
        }
    }
}

__global__ __launch_bounds__(1024) void setup_bk_kernel(
    const int* __restrict__ tok_e, const float* __restrict__ tok_w,
    int* __restrict__ ctrl, int* __restrict__ row_token, float* __restrict__ row_w,
    int* __restrict__ slot, const float* __restrict__ v, float* __restrict__ feats,
    const float* __restrict__ w1, ushort* __restrict__ w1t)
{
    if (blockIdx.x == 0) { setup_body(tok_e, tok_w, ctrl, row_token, row_w, slot); return; }
    if (blockIdx.x <= BB) { bk_body(blockIdx.x - 1, v, feats); return; }
    __shared__ __align__(16) ushort tT4[4 * 4608];
    int tt = (blockIdx.x - 1 - BB) * 4 + (threadIdx.x >> 8);
    int e = tt / (12 * 48);
    int rem = tt - e * 12 * 48;
    int cy = rem / 12;
    int rx = rem - cy * 12;
    tcvt64_body<false>(w1 + (size_t)e * DD * FF, w1t + (size_t)e * FF * DD,
                       DD, FF, rx * 64, cy * 64,
                       tT4 + (threadIdx.x >> 8) * 4608, threadIdx.x & 255);
}

#define MFMAS() do { \
        _Pragma("unroll") \
        for (int i = 0; i < 4; i++) \
            _Pragma("unroll") \
            for (int j = 0; j < 4; j++) \
                acc[i][j] = __builtin_amdgcn_mfma_f32_16x16x32_bf16(afr[i], bfr[j], acc[i][j], 0, 0, 0); \
    } while (0)

// ---------- K5-fused: gemm1 (BM128xBN256, 3-slot, 1-barrier/K32) + w2cvt tail ----------
// Mechanisms kept from the 8-phase template WITHOUT the LDS blow-up that killed
// round 10: BK=32, 3 slots of (128+256)x32 = 72KB total -> 2 blocks/CU for BOTH
// gemm1 and the w2cvt tail (round 10's 144KB forced 1/CU and doubled the tail).
// Single expert per block (BM=128 -> no dual-panel hack). Per K32 tile, ONE
// phase: {issue 3 stages(kt+2) || 8 ds_read_b128 -> lgkmcnt(0) -> 16 MFMA ->
// vmcnt(3) -> barrier}: 1 barrier/tile (round 9 had 2), 16 MFMA/barrier (vs 8),
// counted vmcnt(3) = 2-tile lookahead, loads in flight across barriers; vmcnt(0)
// only at kt=22. Ledger: stage(kt+2)->slot(kt-1), sealed by kt-1's end barrier
// (WAR); vmcnt(3)+barrier at kt's end seals stage(kt+1) (RAW).
// XCD-affine map: bid=8s+x -> XCD x owns tiles x*9..x*9+8 per fx run.
#define G1N   (72 * 12)                 // 864 gemm1 blocks
#define NW2T  (48 * 12 * EE / 2)        // 2304 w2cvt blocks (2 tiles ea)

__global__ __launch_bounds__(512, 4) void gemm1_fused_kernel(
    const ushort* __restrict__ x_bf, const ushort* __restrict__ w1t, const float* __restrict__ b1,
    const int* __restrict__ ctrl, const int* __restrict__ row_token, ushort* __restrict__ H,
    const float* __restrict__ w2, ushort* __restrict__ w2t)
{
    __shared__ __align__(16) ushort SH[36864];   // 72KB: A[3][128*32] + B[3][256*32]
    __shared__ int toks[128];
    int bid = blockIdx.x;
    int tid = threadIdx.x;

    if (bid >= G1N) {
        // ---- w2 [e][3072][768] -> w2t [e][768][3072] with f-perm; 2 tiles/block ----
        int tt = (bid - G1N) * 2 + (tid >> 8);
        int e = tt / (48 * 12);
        int rem = tt - e * 48 * 12;
        int cy = rem / 48;
        int rx = rem - cy * 48;
        ushort* tT = SH + (tid >> 8) * 4608;
        tcvt64_body<true>(w2 + (size_t)e * FF * DD, w2t + (size_t)e * DD * FF,
                          FF, DD, rx * 64, cy * 64, tT, tid & 255);
        return;
    }

    // XCD-affine remap: bid = 8*s + x; fx = s/9, tile = x*9 + s%9 (864 = 8*108)
    int x = bid & 7, s = bid >> 3;
    int fx = s / 9;
    int tile = x * 9 + (s - fx * 9);
    int e = ctrl[24 + tile];
    if (e < 0) return;
    int p0 = tile * 128;
    int f0 = fx * 256;

    ushort* Bb = SH + 3 * 4096;        // B slots base (3 x 8192 ushorts)

    if (tid < 128) { int tk = row_token[p0 + tid]; toks[tid] = tk < 0 ? 0 : tk; }
    __syncthreads();

    int wave = tid >> 6, lane = tid & 63;
    int wr = wave >> 2, wc = wave & 3;            // 2M x 4N wave grid, 64x64/wave

    // ---- stage side: 16 rows (64B each) per gload; 4 lanes/row ----
    int rsub = lane >> 2;                          // 0..15
    int kq = (((lane & 3) ^ ((rsub >> 1) & 3))) * 8;   // proven swizzle (64B rows)
    int tokA = toks[wave * 16 + rsub];
    const ushort* aglob = x_bf + (size_t)tokA * DD + kq;
    const ushort* w1e = w1t + (size_t)e * (FF * DD);
    const ushort* bglob0 = w1e + (size_t)(f0 + wave * 32 + rsub) * DD + kq;
    const ushort* bglob1 = bglob0 + (size_t)16 * DD;
    int dA  = wave * 512;                          // dest within A slot (ushorts)
    int dB0 = wave * 1024, dB1 = dB0 + 512;        // dest within B slot

    // ---- read side ----
    int lm = lane & 15, q = lane >> 4;
    int qx = (q ^ ((lm >> 1) & 3)) * 8;            // proven ds_read swizzle
    int arow = (wr * 64 + lm) * 32;                // + i*512
    int brow = (wc * 64 + lm) * 32;                // + j*512

    floatx4 zero4 = {0.f, 0.f, 0.f, 0.f};
    floatx4 acc[4][4];
    #pragma unroll
    for (int i = 0; i < 4; i++)
        #pragma unroll
        for (int j = 0; j < 4; j++) acc[i][j] = zero4;

    #define STG(SL, kt) do { \
        gload16(aglob  + (kt)*32, SH + (SL)*4096 + dA); \
        gload16(bglob0 + (kt)*32, Bb + (SL)*8192 + dB0); \
        gload16(bglob1 + (kt)*32, Bb + (SL)*8192 + dB1); } while (0)

    #define TILE1(kt, SL, S2) do { \
        bool st_ = (kt) < 22; \
        if (st_) STG(S2, (kt) + 2); \
        bf16x8 afr[4], bfr[4]; \
        _Pragma("unroll") \
        for (int i = 0; i < 4; i++) \
            afr[i] = *(const bf16x8*)(const void*)(SH + (SL)*4096 + arow + i*512 + qx); \
        _Pragma("unroll") \
        for (int j = 0; j < 4; j++) \
            bfr[j] = *(const bf16x8*)(const void*)(Bb + (SL)*8192 + brow + j*512 + qx); \
        asm volatile("s_waitcnt lgkmcnt(0)" ::: "memory"); \
        __builtin_amdgcn_sched_barrier(0); \
        __builtin_amdgcn_s_setprio(1); \
        MFMAS(); \
        __builtin_amdgcn_s_setprio(0); \
        if (st_)             { asm volatile("s_waitcnt vmcnt(3)" ::: "memory"); } \
        else if ((kt) == 22) { asm volatile("s_waitcnt vmcnt(0)" ::: "memory"); } \
        if ((kt) < 23) __builtin_amdgcn_s_barrier(); } while (0)

    // prologue: stage tiles 0,1 (6 gloads); wait stage(0) landed (3 outstanding)
    STG(0, 0); STG(1, 1);
    asm volatile("s_waitcnt vmcnt(3)" ::: "memory");
    __builtin_amdgcn_s_barrier();

    for (int kb = 0; kb < 24; kb += 3) {
        TILE1(kb    , 0, 2);
        TILE1(kb + 1, 1, 0);
        TILE1(kb + 2, 2, 1);
    }
    #undef TILE1
    #undef STG

    // epilogue: paired u32 stores at permuted positions f0+wc*64+jp*32+lm*2
    #pragma unroll
    for (int i = 0; i < 4; i++) {
        #pragma unroll
        for (int jp = 0; jp < 2; jp++) {
            float bias0 = b1[e * FF + f0 + wc*64 + (2*jp)*16 + lm];
            float bias1 = b1[e * FF + f0 + wc*64 + (2*jp+1)*16 + lm];
            #pragma unroll
            for (int r = 0; r < 4; r++) {
                int m = wr*64 + i*16 + q*4 + r;
                float h0 = gelu_f(acc[i][2*jp][r] + bias0);
                float h1 = gelu_f(acc[i][2*jp+1][r] + bias1);
                *(unsigned int*)(H + (size_t)(p0 + m) * FF + f0 + wc*64 + jp*32 + lm*2) = pk2(h0, h1);
            }
        }
    }
}

// ---------- K6: GEMM2 (unchanged) ----------
#define STAGE64(AW, BW, k0) do { \
        _Pragma("unroll") \
        for (int g = 0; g < 4; g++) { \
            gload16(ag[g] + (k0), (AW) + g*8*64); \
            gload16(bg[g] + (k0), (BW) + g*8*64); \
        } } while (0)

#define LOADFR64(APTR, BPTR, QX) do { \
        _Pragma("unroll") \
        for (int i = 0; i < 4; i++) \
            afr[i] = *(const bf16x8*)(const void*)((APTR) + (wm + i*16 + lm) * 64 + (QX)); \
        _Pragma("unroll") \
        for (int j = 0; j < 4; j++) \
            bfr[j] = *(const bf16x8*)(const void*)((BPTR) + (wn + j*16 + lm) * 64 + (QX)); \
    } while (0)

#define PIPE64(NK) do { \
    STAGE64(AsW0, BsW0, 0); \
    STAGE64(AsW1, BsW1, 64); \
    for (int ks = 0; ks < (NK); ks++) { \
        int cur = ks & 1; \
        const ushort* Ab = cur ? As[1] : As[0]; \
        const ushort* Bb = cur ? Bs[1] : Bs[0]; \
        ushort* AsN = cur ? AsW1 : AsW0; \
        ushort* BsN = cur ? BsW1 : BsW0; \
        if (ks < (NK) - 1) { asm volatile("s_waitcnt vmcnt(8)" ::: "memory"); } \
        else               { asm volatile("s_waitcnt vmcnt(0)" ::: "memory"); } \
        __builtin_amdgcn_s_barrier(); \
        { \
            bf16x8 afr[4], bfr[4]; \
            LOADFR64(Ab, Bb, qx0); \
            __builtin_amdgcn_s_setprio(1); \
            MFMAS(); \
            __builtin_amdgcn_s_setprio(0); \
        } \
        { \
            bf16x8 afr[4], bfr[4]; \
            LOADFR64(Ab, Bb, qx0 ^ 32); \
            asm volatile("s_waitcnt lgkmcnt(0)" ::: "memory"); \
            __builtin_amdgcn_sched_barrier(0); \
            __builtin_amdgcn_s_barrier(); \
            if (ks + 2 < (NK)) STAGE64(AsN, BsN, ks*64 + 128); \
            __builtin_amdgcn_s_setprio(1); \
            MFMAS(); \
            __builtin_amdgcn_s_setprio(0); \
        } \
    } } while (0)

__global__ __launch_bounds__(256) void gemm2_kernel(
    const ushort* __restrict__ H, const ushort* __restrict__ w2t, const float* __restrict__ b2,
    const int* __restrict__ ctrl, const float* __restrict__ row_w, float* __restrict__ Y)
{
    int tile = blockIdx.x;
    int e = ctrl[24 + tile];
    if (e < 0) return;
    int p0 = tile * 128;
    int d0 = blockIdx.y * 128;

    __shared__ ushort As[2][128 * 64];
    __shared__ ushort Bs[2][128 * 64];

    int tid = threadIdx.x;
    int wave = tid >> 6, lane = tid & 63;
    int srow = lane >> 3;
    int kq = (((lane & 7) ^ (srow & 7))) * 8;
    const ushort* ag[4];
    #pragma unroll
    for (int g = 0; g < 4; g++)
        ag[g] = H + (size_t)(p0 + wave*32 + g*8 + srow) * FF + kq;
    const ushort* w2e = w2t + (size_t)e * (DD * FF);
    const ushort* bg[4];
    #pragma unroll
    for (int g = 0; g < 4; g++)
        bg[g] = w2e + (size_t)(d0 + wave*32 + g*8 + srow) * FF + kq;
    ushort* AsW0 = &As[0][wave * 32 * 64];
    ushort* BsW0 = &Bs[0][wave * 32 * 64];
    ushort* AsW1 = &As[1][wave * 32 * 64];
    ushort* BsW1 = &Bs[1][wave * 32 * 64];

    floatx4 zero4 = {0.f, 0.f, 0.f, 0.f};
    floatx4 acc[4][4];
    #pragma unroll
    for (int i = 0; i < 4; i++)
        #pragma unroll
        for (int j = 0; j < 4; j++) acc[i][j] = zero4;

    int wm = (wave & 1) * 64, wn = (wave >> 1) * 64;
    int lm = lane & 15, q = lane >> 4;
    int qx0 = (q ^ (lm & 7)) * 8;

    PIPE64(FF/64);

    #pragma unroll
    for (int i = 0; i < 4; i++) {
        #pragma unroll
        for (int j = 0; j < 4; j++) {
            int n = wn + j*16 + lm;
            float bias = b2[e * DD + d0 + n];
            #pragma unroll
            for (int r = 0; r < 4; r++) {
                int m = wm + i*16 + q*4 + r;
                float wgt = row_w[p0 + m];
                Y[(size_t)(p0 + m) * DD + d0 + n] = wgt * (acc[i][j][r] + bias);
            }
        }
    }
}

// ---------- K7: final combine (unchanged) ----------
__global__ __launch_bounds__(256) void final_kernel(
    const float* __restrict__ Y, const int* __restrict__ slot, const float* __restrict__ feats,
    const float* __restrict__ out_w, const float* __restrict__ out_b,
    const float* __restrict__ bk_scale, float* __restrict__ out)
{
    int idx = blockIdx.x * 256 + threadIdx.x;
    int base = idx * 4;
    int t = base / DD;
    int d = base - t * DD;
    int p0 = slot[2*t], p1 = slot[2*t + 1];
    const float4 ya = *(const float4*)(Y + (size_t)p0 * DD + d);
    const float4 yb = *(const float4*)(Y + (size_t)p1 * DD + d);
    float f0 = feats[2*t], f1 = feats[2*t + 1];
    f0 = fminf(fmaxf(f0, -10.f), 10.f);
    f1 = fminf(fmaxf(f1, -10.f), 10.f);
    float ff[4] = {ya.x + yb.x, ya.y + yb.y, ya.z + yb.z, ya.w + yb.w};
    float4 o;
    float* op = (float*)&o;
    #pragma unroll
    for (int u = 0; u < 4; u++) {
        float spec = f0 * out_w[d + u] + f1 * out_w[DD + d + u] + out_b[d + u];
        op[u] = ff[u] + bk_scale[d + u] * spec;
    }
    *(float4*)(out + base) = o;
}

extern "C" void kernel_launch(void* const* d_in, const int* in_sizes, int n_in,
                              void* d_out, int out_size, void* d_ws, size_t ws_size,
                              hipStream_t stream)
{
    const float* x      = (const float*)d_in[0];
    const float* v_w    = (const float*)d_in[1];
    const float* v_b    = (const float*)d_in[2];
    const float* gate_w = (const float*)d_in[3];
    const float* gate_b = (const float*)d_in[4];
    const float* w1     = (const float*)d_in[5];
    const float* b1     = (const float*)d_in[6];
    const float* w2     = (const float*)d_in[7];
    const float* b2     = (const float*)d_in[8];
    const float* out_w  = (const float*)d_in[9];
    const float* out_b  = (const float*)d_in[10];
    const float* bk_s   = (const float*)d_in[11];

    char* ws = (char*)d_ws;
    int*    ctrl    = (int*)(ws + OFF_CTRL);
    float*  v       = (float*)(ws + OFF_V);
    int*    tok_e   = (int*)(ws + OFF_TOKE);
    float*  tok_w   = (float*)(ws + OFF_TOKW);
    int*    row_tok = (int*)(ws + OFF_ROWTOK);
    float*  row_w   = (float*)(ws + OFF_ROWW);
    int*    slot    = (int*)(ws + OFF_SLOT);
    float*  feats   = (float*)(ws + OFF_FEATS);
    ushort* w2t     = (ushort*)(ws + OFF_W2T);
    ushort* x_bf    = (ushort*)(ws + OFF_XBF);
    ushort* w1t     = (ushort*)(ws + OFF_W1T);
    ushort* H       = (ushort*)(ws + OFF_H);
    float*  Y       = (float*)(ws + OFF_Y);
    float*  out     = (float*)d_out;

    prep0_kernel<<<NB_CVT + NB_ROUTE, 256, 0, stream>>>(
        x, x_bf, v_w, v_b, gate_w, gate_b, v, tok_e, tok_w);
    setup_bk_kernel<<<1 + BB + NB_W1T4, 1024, 0, stream>>>(
        tok_e, tok_w, ctrl, row_tok, row_w, slot, v, feats, w1, w1t);
    gemm1_fused_kernel<<<G1N + NW2T, 512, 0, stream>>>(x_bf, w1t, b1, ctrl, row_tok, H, w2, w2t);
    gemm2_kernel<<<dim3(TILES, DD / 128), 256, 0, stream>>>(H, w2t, b2, ctrl, row_w, Y);
    final_kernel<<<(TOK * DD) / 1024, 256, 0, stream>>>(Y, slot, feats, out_w, out_b, bk_s, out);
}